// Round 9
// baseline (886.178 us; speedup 1.0000x reference)
//
#include <hip/hip_runtime.h>

#define D128 128

typedef __attribute__((ext_vector_type(8))) short bf16x8;
typedef __attribute__((ext_vector_type(4))) float f32x4;
typedef unsigned short u16;
typedef unsigned int u32;

__device__ __forceinline__ u16 f2b(float f) {
  union { float f; u32 u; } x; x.f = f;
  u32 r = x.u + 0x7fffu + ((x.u >> 16) & 1u);
  return (u16)(r >> 16);
}
__device__ __forceinline__ float b2f(short s) {
  union { u32 u; float f; } x; x.u = ((u32)(unsigned short)s) << 16; return x.f;
}

#define GLD16(gp, lp) __builtin_amdgcn_global_load_lds( \
    (const __attribute__((address_space(1))) void*)(gp), \
    (__attribute__((address_space(3))) void*)(lp), 16, 0, 0)

// ---- K1: cvt x -> B0 (combined node space) + W -> Wcat  ||  degree atomics ----
__global__ __launch_bounds__(256) void cvt_deg_k(const float* __restrict__ xc, const float* __restrict__ xp,
                                                 const float* __restrict__ Wl, const float* __restrict__ Wr,
                                                 const int* __restrict__ src, const int* __restrict__ dst,
                                                 u16* __restrict__ B0, u16* __restrict__ Wcat,
                                                 int* __restrict__ deg, int NP, int NT, int E) {
  const int nqx = NT * 32;          // float4 quads over x
  const int ncvt = nqx + 49152;     // + W quads
  const int TOT = ncvt + E;         // + edges (degree work)
  for (int i = blockIdx.x * 256 + threadIdx.x; i < TOT; i += gridDim.x * 256) {
    if (i < nqx) {
      const int r = i >> 5, c4 = (i & 31) << 2;
      const float* sp = (r < NP) ? &xp[(size_t)r * D128 + c4]
                                 : &xc[(size_t)(r - NP) * D128 + c4];
      float4 f = *(const float4*)sp;
      uint2 u;
      u.x = (u32)f2b(f.x) | ((u32)f2b(f.y) << 16);
      u.y = (u32)f2b(f.z) | ((u32)f2b(f.w) << 16);
      *(uint2*)&B0[(size_t)i * 4] = u;
    } else if (i < ncvt) {
      const int t = (i - nqx) * 4;
      const int slice = t >> 15, j = (t >> 8) & 127, k = t & 255;
      const float* sw = (k < 128) ? &Wl[(size_t)slice * 16384 + j * 128 + k]
                                  : &Wr[(size_t)slice * 16384 + j * 128 + (k - 128)];
      float4 f = *(const float4*)sw;
      uint2 u;
      u.x = (u32)f2b(f.x) | ((u32)f2b(f.y) << 16);
      u.y = (u32)f2b(f.z) | ((u32)f2b(f.w) << 16);
      *(uint2*)&Wcat[t] = u;
    } else {
      const int e = i - ncvt;
      atomicAdd(&deg[dst[e]], 1);
      atomicAdd(&deg[NP + src[e]], 1);
    }
  }
}

// ---- K2: full exclusive scan in one dispatch ----
__global__ __launch_bounds__(256) void scan_k(const int* __restrict__ deg, int* __restrict__ offp, int NT) {
  __shared__ int sh[256];
  const int c = blockIdx.x;
  const int tid = threadIdx.x;
  int pre = 0;
  const int lim = c * 2048;
  for (int i = tid; i < lim; i += 256) pre += deg[i];
  sh[tid] = pre; __syncthreads();
#pragma unroll
  for (int o = 128; o > 0; o >>= 1) {
    if (tid < o) sh[tid] += sh[tid + o];
    __syncthreads();
  }
  const int base_pre = sh[0];
  __syncthreads();
  const int base = lim + tid * 8;
  int v[8]; int s = 0;
#pragma unroll
  for (int u = 0; u < 8; ++u) { int i = base + u; v[u] = (i < NT) ? deg[i] : 0; s += v[u]; }
  sh[tid] = s; __syncthreads();
#pragma unroll
  for (int o = 1; o < 256; o <<= 1) {
    int t = (tid >= o) ? sh[tid - o] : 0;
    __syncthreads();
    sh[tid] += t;
    __syncthreads();
  }
  int run = sh[tid] - s + base_pre;
#pragma unroll
  for (int u = 0; u < 8; ++u) { int i = base + u; if (i < NT) offp[i] = run; run += v[u]; }
}

// ---- K3: fill adjacency ----
__global__ __launch_bounds__(256) void fill_k(const int* __restrict__ src, const int* __restrict__ dst,
                                              const int* __restrict__ offp, int* cur, int* adj,
                                              int NP, int E) {
  int e = blockIdx.x * 256 + threadIdx.x;
  if (e >= E) return;
  const int s = src[e], d = dst[e];
  const int cn = NP + s;
  int pp = atomicAdd(&cur[d], 1);  adj[offp[d] + pp] = cn;
  int pc = atomicAdd(&cur[cn], 1); adj[offp[cn] + pc] = d;
}

// ---- agg: XCD-sliced. Block b owns 16-col slice (b&7); with %8 block->XCD round-robin,
// each XCD's L2 only sees a 3.84MB column-slice of the node table -> gathers become L2 hits.
// One lane per (node, slice); serial neighbor loop with 2-deep index prefetch.
// 512 long-lived blocks (all co-resident -> stable XCD pinning).
__global__ __launch_bounds__(256) void agg_k(const u16* __restrict__ hcur, u16* __restrict__ hnext,
                                             const int* __restrict__ adj, const int* __restrict__ offp,
                                             const int* __restrict__ deg, int NT) {
  const int s16 = (blockIdx.x & 7) * 16;          // column base of this block's slice
  const int nch = gridDim.x >> 3;                 // node-chunks stride (blocks per slice)
  const int tid = threadIdx.x;
  for (int base = (blockIdx.x >> 3) * 256; base < NT; base += nch * 256) {
    const int v = base + tid;
    if (v < NT) {
      const int so = offp[v], cnt = deg[v];
      float ac[16];
#pragma unroll
      for (int k = 0; k < 16; ++k) ac[k] = 0.f;
      int idx = (cnt > 0) ? adj[so] : 0;
      for (int j = 0; j < cnt; ++j) {
        const int nidx = (j + 1 < cnt) ? adj[so + j + 1] : 0;   // prefetch next index
        const u16* rp = &hcur[(size_t)idx * D128 + s16];
        bf16x8 r0 = *(const bf16x8*)rp;
        bf16x8 r1 = *(const bf16x8*)(rp + 8);
#pragma unroll
        for (int k = 0; k < 8; ++k) { ac[k] += b2f(r0[k]); ac[8 + k] += b2f(r1[k]); }
        idx = nidx;
      }
      const float inv = (cnt > 0) ? 1.f / (float)cnt : 0.f;
      uint4 p0, p1;
      p0.x = (u32)f2b(ac[0] * inv)  | ((u32)f2b(ac[1] * inv) << 16);
      p0.y = (u32)f2b(ac[2] * inv)  | ((u32)f2b(ac[3] * inv) << 16);
      p0.z = (u32)f2b(ac[4] * inv)  | ((u32)f2b(ac[5] * inv) << 16);
      p0.w = (u32)f2b(ac[6] * inv)  | ((u32)f2b(ac[7] * inv) << 16);
      p1.x = (u32)f2b(ac[8] * inv)  | ((u32)f2b(ac[9] * inv) << 16);
      p1.y = (u32)f2b(ac[10] * inv) | ((u32)f2b(ac[11] * inv) << 16);
      p1.z = (u32)f2b(ac[12] * inv) | ((u32)f2b(ac[13] * inv) << 16);
      p1.w = (u32)f2b(ac[14] * inv) | ((u32)f2b(ac[15] * inv) << 16);
      uint4* op = (uint4*)&hnext[(size_t)v * D128 + s16];
      op[0] = p0;
      op[1] = p1;
    }
  }
}

// ---- gemm: hnext = relu(concat(hnext, hcur) @ Wcat_l^T + bias), in-place ----
__global__ __launch_bounds__(256) void gemm_both_k(u16* __restrict__ hnext, const u16* __restrict__ hcur,
                                                   const u16* __restrict__ Wcat_l, const float* __restrict__ bl_l,
                                                   int NP, int NT, int tilesP) {
  __shared__ u16 As[128 * 64];
  __shared__ u16 Bs[128 * 64];
  const int t = blockIdx.x;
  const bool isP = t < tilesP;
  const int rbase = isP ? t * 128 : NP + (t - tilesP) * 128;
  const int hi = isP ? NP : NT;
  const u16* __restrict__ W = Wcat_l + (isP ? 0 : 32768);
  const float* __restrict__ bias = bl_l + (isP ? 0 : 128);

  const int tid = threadIdx.x;
  const int w = tid >> 6, lane = tid & 63;
  const int wr = w >> 1, wc = w & 1;
  const int l15 = lane & 15, chi = lane >> 4;

  f32x4 acc[4][4];
#pragma unroll
  for (int m = 0; m < 4; ++m)
#pragma unroll
    for (int n = 0; n < 4; ++n) acc[m][n] = (f32x4){0.f, 0.f, 0.f, 0.f};

  for (int ks = 0; ks < 4; ++ks) {
    const int k0 = ks * 64;
    const u16* Xsrc = (k0 < 128) ? hnext : hcur;
    const int kb = k0 & 127;
    if (ks) __syncthreads();
#pragma unroll
    for (int q = 0; q < 4; ++q) {
      const int ibase = w * 256 + q * 64;
      const int i = ibase + lane;
      const int r = i >> 3;
      const int cg = (i & 7) ^ (r & 7);
      int rr = rbase + r; if (rr >= hi) rr = hi - 1;
      GLD16(Xsrc + (size_t)rr * D128 + kb + cg * 8, (char*)As + ibase * 16);
      GLD16(W + (size_t)r * 256 + k0 + cg * 8, (char*)Bs + ibase * 16);
    }
    __syncthreads();
#pragma unroll
    for (int kk = 0; kk < 2; ++kk) {
      bf16x8 a[4], bfr[4];
      const int c = kk * 4 + chi;
#pragma unroll
      for (int m = 0; m < 4; ++m) {
        const int r = wr * 64 + m * 16 + l15;
        a[m] = *(const bf16x8*)((const char*)As + (r * 8 + (c ^ (r & 7))) * 16);
      }
#pragma unroll
      for (int n = 0; n < 4; ++n) {
        const int j = wc * 64 + n * 16 + l15;
        bfr[n] = *(const bf16x8*)((const char*)Bs + (j * 8 + (c ^ (j & 7))) * 16);
      }
#pragma unroll
      for (int m = 0; m < 4; ++m)
#pragma unroll
        for (int n = 0; n < 4; ++n)
          acc[m][n] = __builtin_amdgcn_mfma_f32_16x16x32_bf16(a[m], bfr[n], acc[m][n], 0, 0, 0);
    }
  }
#pragma unroll
  for (int n = 0; n < 4; ++n) {
    const int col = wc * 64 + n * 16 + l15;
    const float bv = bias[col];
#pragma unroll
    for (int m = 0; m < 4; ++m) {
      const int rb2 = rbase + wr * 64 + m * 16 + chi * 4;
#pragma unroll
      for (int q = 0; q < 4; ++q) {
        const int row = rb2 + q;
        if (row < hi) {
          float vv = acc[m][n][q] + bv;
          vv = vv > 0.f ? vv : 0.f;
          hnext[(size_t)row * D128 + col] = f2b(vv);
        }
      }
    }
  }
}

// ---- decoder: 2 edges per wave (32-lane halves), 16B h-reads, plain vector x-writes ----
__global__ __launch_bounds__(256) void decoder_k(const u16* __restrict__ hf,
                                                 const int* __restrict__ rowi, const int* __restrict__ coli,
                                                 const float* __restrict__ Wd, const float* __restrict__ bd,
                                                 float* __restrict__ out, int NP, int EL) {
  typedef __attribute__((ext_vector_type(8))) unsigned short u16x8;
  const int lane = threadIdx.x & 63;
  const int half = lane >> 5;            // which edge of the pair
  const int l32 = lane & 31;             // lane within edge
  const int wid = blockIdx.x * 4 + (threadIdx.x >> 6);
  const int nw = gridDim.x * 4;
  float wvv[8];
#pragma unroll
  for (int k = 0; k < 8; ++k) wvv[k] = Wd[l32 * 8 + k];
  const float bdv = bd[0];
  for (int e = wid * 2 + half; e < EL; e += nw * 2) {
    const int r = rowi[e], c = coli[e];
    const size_t hrow = (l32 < 16) ? ((size_t)(NP + r) * D128 + l32 * 8)
                                   : ((size_t)c * D128 + (l32 - 16) * 8);
    const u16x8 hb = *(const u16x8*)&hf[hrow];
    float x0 = b2f((short)hb[0]), x1 = b2f((short)hb[1]);
    float x2 = b2f((short)hb[2]), x3 = b2f((short)hb[3]);
    float x4 = b2f((short)hb[4]), x5 = b2f((short)hb[5]);
    float x6 = b2f((short)hb[6]), x7 = b2f((short)hb[7]);
    float p = x0 * wvv[0] + x1 * wvv[1] + x2 * wvv[2] + x3 * wvv[3]
            + x4 * wvv[4] + x5 * wvv[5] + x6 * wvv[6] + x7 * wvv[7];
#pragma unroll
    for (int m = 1; m < 32; m <<= 1) p += __shfl_xor(p, m, 64);
    float* xo = out + (size_t)EL + (size_t)e * 256 + l32 * 8;
    f32x4 lo = {x0, x1, x2, x3};
    f32x4 hi2 = {x4, x5, x6, x7};
    *(f32x4*)xo = lo;
    *(f32x4*)(xo + 4) = hi2;
    if (l32 == 0) out[e] = p + bdv;
  }
}

// ---------------- host ----------------

extern "C" void kernel_launch(void* const* d_in, const int* in_sizes, int n_in,
                              void* d_out, int out_size, void* d_ws, size_t ws_size,
                              hipStream_t stream) {
  const float* x_chem = (const float*)d_in[0];
  const float* x_prot = (const float*)d_in[1];
  const float* Wl = (const float*)d_in[2];
  const float* bl = (const float*)d_in[3];
  const float* Wr = (const float*)d_in[4];
  const float* Wd = (const float*)d_in[5];
  const float* bd = (const float*)d_in[6];
  const int* src = (const int*)d_in[7];
  const int* dst = (const int*)d_in[8];
  const int* row = (const int*)d_in[9];
  const int* col = (const int*)d_in[10];

  int NC = in_sizes[0] / D128;
  int NP = in_sizes[1] / D128;
  int E  = in_sizes[7];
  int EL = in_sizes[9];
  int NT = NP + NC;
  int nchunk = (NT + 2047) / 2048;
  float* out = (float*)d_out;

  char* w = (char*)d_ws;
  size_t szT = (size_t)NT * D128 * 2;
  u16* B0 = (u16*)w; w += szT;
  u16* B1 = (u16*)w; w += szT;
  u16* B2 = (u16*)w; w += szT;
  u16* Wcat = (u16*)w; w += (size_t)6 * 128 * 256 * 2;
  int* deg  = (int*)w; w += (size_t)NT * 4;   // deg,cur contiguous (one memset)
  int* cur  = (int*)w; w += (size_t)NT * 4;
  int* offp = (int*)w; w += (size_t)NT * 4;
  int* adj  = (int*)w; w += (size_t)2 * E * 4;
  if ((size_t)(w - (char*)d_ws) > ws_size) return;

  (void)hipMemsetAsync(deg, 0, (size_t)2 * NT * 4, stream);

  cvt_deg_k<<<2048, 256, 0, stream>>>(x_chem, x_prot, Wl, Wr, src, dst,
                                      B0, Wcat, deg, NP, NT, E);
  scan_k<<<nchunk, 256, 0, stream>>>(deg, offp, NT);
  fill_k<<<(E + 255) / 256, 256, 0, stream>>>(src, dst, offp, cur, adj, NP, E);

  const int tilesP = (NP + 127) >> 7;
  const int tilesC = (NC + 127) >> 7;
  u16* bufs[4] = {B0, B1, B2, B1};   // L0: B0->B1, L1: B1->B2, L2: B2->B1
  for (int l = 0; l < 3; ++l) {
    const u16* hcur = bufs[l];
    u16* hnext = bufs[l + 1];
    agg_k<<<512, 256, 0, stream>>>(hcur, hnext, adj, offp, deg, NT);
    gemm_both_k<<<tilesP + tilesC, 256, 0, stream>>>(hnext, hcur,
                                                     Wcat + (size_t)l * 65536,
                                                     bl + (size_t)l * 256,
                                                     NP, NT, tilesP);
  }

  decoder_k<<<2048, 256, 0, stream>>>(B1, row, col, Wd, bd, out, NP, EL);
}

// Round 11
// 625.426 us; speedup vs baseline: 1.4169x; 1.4169x over previous
//
#include <hip/hip_runtime.h>

#define D128 128

typedef __attribute__((ext_vector_type(8))) short bf16x8;
typedef __attribute__((ext_vector_type(4))) float f32x4;
typedef unsigned short u16;
typedef unsigned int u32;

__device__ __forceinline__ u16 f2b(float f) {
  union { float f; u32 u; } x; x.f = f;
  u32 r = x.u + 0x7fffu + ((x.u >> 16) & 1u);
  return (u16)(r >> 16);
}
__device__ __forceinline__ float b2f(short s) {
  union { u32 u; float f; } x; x.u = ((u32)(unsigned short)s) << 16; return x.f;
}

// ---- K1: cvt x -> B0 (combined node space) + W -> Wcat || degree atomics ----
// deg/cur zeroed by preceding memset node.
__global__ __launch_bounds__(256) void cvt_deg_k(const float* __restrict__ xc, const float* __restrict__ xp,
                                                 const float* __restrict__ Wl, const float* __restrict__ Wr,
                                                 const int* __restrict__ src, const int* __restrict__ dst,
                                                 u16* __restrict__ B0, u16* __restrict__ Wcat,
                                                 int* __restrict__ deg, int NP, int NT, int E) {
  const int nqx = NT * 32;          // float4 quads over x
  const int ncvt = nqx + 49152;     // + W quads
  const int TOT = ncvt + E;         // + edges (degree work)
  for (int i = blockIdx.x * 256 + threadIdx.x; i < TOT; i += gridDim.x * 256) {
    if (i < nqx) {
      const int r = i >> 5, c4 = (i & 31) << 2;
      const float* sp = (r < NP) ? &xp[(size_t)r * D128 + c4]
                                 : &xc[(size_t)(r - NP) * D128 + c4];
      float4 f = *(const float4*)sp;
      uint2 u;
      u.x = (u32)f2b(f.x) | ((u32)f2b(f.y) << 16);
      u.y = (u32)f2b(f.z) | ((u32)f2b(f.w) << 16);
      *(uint2*)&B0[(size_t)i * 4] = u;
    } else if (i < ncvt) {
      const int t = (i - nqx) * 4;
      const int slice = t >> 15, j = (t >> 8) & 127, k = t & 255;
      const float* sw = (k < 128) ? &Wl[(size_t)slice * 16384 + j * 128 + k]
                                  : &Wr[(size_t)slice * 16384 + j * 128 + (k - 128)];
      float4 f = *(const float4*)sw;
      uint2 u;
      u.x = (u32)f2b(f.x) | ((u32)f2b(f.y) << 16);
      u.y = (u32)f2b(f.z) | ((u32)f2b(f.w) << 16);
      *(uint2*)&Wcat[t] = u;
    } else {
      const int e = i - ncvt;
      atomicAdd(&deg[dst[e]], 1);
      atomicAdd(&deg[NP + src[e]], 1);
    }
  }
}

// ---- K2: full exclusive scan in one dispatch ----
__global__ __launch_bounds__(256) void scan_k(const int* __restrict__ deg, int* __restrict__ offp, int NT) {
  __shared__ int sh[256];
  const int c = blockIdx.x;
  const int tid = threadIdx.x;
  int pre = 0;
  const int lim = c * 2048;
  for (int i = tid; i < lim; i += 256) pre += deg[i];
  sh[tid] = pre; __syncthreads();
#pragma unroll
  for (int o = 128; o > 0; o >>= 1) {
    if (tid < o) sh[tid] += sh[tid + o];
    __syncthreads();
  }
  const int base_pre = sh[0];
  __syncthreads();
  const int base = lim + tid * 8;
  int v[8]; int s = 0;
#pragma unroll
  for (int u = 0; u < 8; ++u) { int i = base + u; v[u] = (i < NT) ? deg[i] : 0; s += v[u]; }
  sh[tid] = s; __syncthreads();
#pragma unroll
  for (int o = 1; o < 256; o <<= 1) {
    int t = (tid >= o) ? sh[tid - o] : 0;
    __syncthreads();
    sh[tid] += t;
    __syncthreads();
  }
  int run = sh[tid] - s + base_pre;
#pragma unroll
  for (int u = 0; u < 8; ++u) { int i = base + u; if (i < NT) offp[i] = run; run += v[u]; }
}

// ---- K3: fill adjacency ----
__global__ __launch_bounds__(256) void fill_k(const int* __restrict__ src, const int* __restrict__ dst,
                                              const int* __restrict__ offp, int* cur, int* adj,
                                              int NP, int E) {
  int e = blockIdx.x * 256 + threadIdx.x;
  if (e >= E) return;
  const int s = src[e], d = dst[e];
  const int cn = NP + s;
  int pp = atomicAdd(&cur[d], 1);  adj[offp[d] + pp] = cn;
  int pc = atomicAdd(&cur[cn], 1); adj[offp[cn] + pc] = d;
}

// ---- fused layer: phase1 agg-mean -> LDS (swizzled), phase2 MFMA GEMM -> hnext ----
// 128-row tile per block, 256 threads. Phase1: 16 groups x 16 lanes, 8 rows/group,
// 8-deep neighbor gather ILP (128 gathers in flight per block). Phase2: R3-proven
// MFMA with A(mean) from LDS, A(hold) + B(W) direct global (L2-hot).
__global__ __launch_bounds__(256) void layer_k(const u16* __restrict__ hcur, u16* __restrict__ hnext,
                                               const int* __restrict__ adj, const int* __restrict__ offp,
                                               const int* __restrict__ deg,
                                               const u16* __restrict__ Wcat_l, const float* __restrict__ bl_l,
                                               int NP, int NT, int tilesP) {
  __shared__ u16 Am[128 * 128];
  const int t = blockIdx.x;
  const bool isP = t < tilesP;
  const int rbase = isP ? t * 128 : NP + (t - tilesP) * 128;
  const int hi = isP ? NP : NT;
  const u16* __restrict__ W = Wcat_l + (isP ? 0 : 32768);
  const float* __restrict__ bias = bl_l + (isP ? 0 : 128);
  const int tid = threadIdx.x;

  // ---- phase 1: neighbor means into Am (XOR-swizzled bf16) ----
  {
    const int g = tid >> 4;        // group 0..15
    const int l16 = tid & 15;      // 16B col-chunk
    const int half = l16 >> 3, cc = l16 & 7;
    for (int rr = g * 8; rr < g * 8 + 8; ++rr) {
      int v = rbase + rr; if (v >= hi) v = hi - 1;
      const int so = offp[v], cnt = deg[v];
      float ac[8] = {0.f, 0.f, 0.f, 0.f, 0.f, 0.f, 0.f, 0.f};
      int j = 0;
      for (; j + 8 <= cnt; j += 8) {
        const int i0 = adj[so + j],     i1 = adj[so + j + 1];
        const int i2 = adj[so + j + 2], i3 = adj[so + j + 3];
        const int i4 = adj[so + j + 4], i5 = adj[so + j + 5];
        const int i6 = adj[so + j + 6], i7 = adj[so + j + 7];
        bf16x8 r0 = *(const bf16x8*)&hcur[(size_t)i0 * D128 + l16 * 8];
        bf16x8 r1 = *(const bf16x8*)&hcur[(size_t)i1 * D128 + l16 * 8];
        bf16x8 r2 = *(const bf16x8*)&hcur[(size_t)i2 * D128 + l16 * 8];
        bf16x8 r3 = *(const bf16x8*)&hcur[(size_t)i3 * D128 + l16 * 8];
        bf16x8 r4 = *(const bf16x8*)&hcur[(size_t)i4 * D128 + l16 * 8];
        bf16x8 r5 = *(const bf16x8*)&hcur[(size_t)i5 * D128 + l16 * 8];
        bf16x8 r6 = *(const bf16x8*)&hcur[(size_t)i6 * D128 + l16 * 8];
        bf16x8 r7 = *(const bf16x8*)&hcur[(size_t)i7 * D128 + l16 * 8];
#pragma unroll
        for (int k = 0; k < 8; ++k)
          ac[k] += ((b2f(r0[k]) + b2f(r1[k])) + (b2f(r2[k]) + b2f(r3[k])))
                 + ((b2f(r4[k]) + b2f(r5[k])) + (b2f(r6[k]) + b2f(r7[k])));
      }
      for (; j + 4 <= cnt; j += 4) {
        const int i0 = adj[so + j],     i1 = adj[so + j + 1];
        const int i2 = adj[so + j + 2], i3 = adj[so + j + 3];
        bf16x8 r0 = *(const bf16x8*)&hcur[(size_t)i0 * D128 + l16 * 8];
        bf16x8 r1 = *(const bf16x8*)&hcur[(size_t)i1 * D128 + l16 * 8];
        bf16x8 r2 = *(const bf16x8*)&hcur[(size_t)i2 * D128 + l16 * 8];
        bf16x8 r3 = *(const bf16x8*)&hcur[(size_t)i3 * D128 + l16 * 8];
#pragma unroll
        for (int k = 0; k < 8; ++k)
          ac[k] += (b2f(r0[k]) + b2f(r1[k])) + (b2f(r2[k]) + b2f(r3[k]));
      }
      for (; j < cnt; ++j) {
        const int i0 = adj[so + j];
        bf16x8 r0 = *(const bf16x8*)&hcur[(size_t)i0 * D128 + l16 * 8];
#pragma unroll
        for (int k = 0; k < 8; ++k) ac[k] += b2f(r0[k]);
      }
      const float inv = (cnt > 0) ? 1.f / (float)cnt : 0.f;
      uint4 pk;
      pk.x = (u32)f2b(ac[0] * inv) | ((u32)f2b(ac[1] * inv) << 16);
      pk.y = (u32)f2b(ac[2] * inv) | ((u32)f2b(ac[3] * inv) << 16);
      pk.z = (u32)f2b(ac[4] * inv) | ((u32)f2b(ac[5] * inv) << 16);
      pk.w = (u32)f2b(ac[6] * inv) | ((u32)f2b(ac[7] * inv) << 16);
      *(uint4*)&Am[rr * 128 + half * 64 + ((cc ^ (rr & 7)) << 3)] = pk;
    }
  }
  __syncthreads();

  // ---- phase 2: GEMM hnext = relu(concat(mean, hold) @ W^T + bias) ----
  {
    const int w = tid >> 6, lane = tid & 63;
    const int wr = w >> 1, wc = w & 1;
    const int l15 = lane & 15, chi = lane >> 4;
    f32x4 acc[4][4];
#pragma unroll
    for (int m = 0; m < 4; ++m)
#pragma unroll
      for (int n = 0; n < 4; ++n) acc[m][n] = (f32x4){0.f, 0.f, 0.f, 0.f};

#pragma unroll
    for (int ks = 0; ks < 4; ++ks) {
#pragma unroll
      for (int kk = 0; kk < 2; ++kk) {
        bf16x8 a[4], bfr[4];
#pragma unroll
        for (int m = 0; m < 4; ++m) {
          const int row = wr * 64 + m * 16 + l15;
          if (ks < 2) {
            a[m] = *(const bf16x8*)&Am[row * 128 + ks * 64 + (((kk * 4 + chi) ^ (row & 7)) << 3)];
          } else {
            int rg = rbase + row; if (rg >= hi) rg = hi - 1;
            a[m] = *(const bf16x8*)&hcur[(size_t)rg * D128 + (ks - 2) * 64 + kk * 32 + chi * 8];
          }
        }
#pragma unroll
        for (int n = 0; n < 4; ++n) {
          const int jc = wc * 64 + n * 16 + l15;
          bfr[n] = *(const bf16x8*)&W[jc * 256 + ks * 64 + kk * 32 + chi * 8];
        }
#pragma unroll
        for (int m = 0; m < 4; ++m)
#pragma unroll
          for (int n = 0; n < 4; ++n)
            acc[m][n] = __builtin_amdgcn_mfma_f32_16x16x32_bf16(a[m], bfr[n], acc[m][n], 0, 0, 0);
      }
    }
#pragma unroll
    for (int n = 0; n < 4; ++n) {
      const int col = wc * 64 + n * 16 + l15;
      const float bv = bias[col];
#pragma unroll
      for (int m = 0; m < 4; ++m) {
        const int rb2 = rbase + wr * 64 + m * 16 + chi * 4;
#pragma unroll
        for (int q = 0; q < 4; ++q) {
          const int row = rb2 + q;
          if (row < hi) {
            float vv = acc[m][n][q] + bv;
            vv = vv > 0.f ? vv : 0.f;
            hnext[(size_t)row * D128 + col] = f2b(vv);
          }
        }
      }
    }
  }
}

// ---- decoder: one edge per wave (R6-proven) ----
__global__ __launch_bounds__(256) void decoder_k(const u16* __restrict__ hf,
                                                 const int* __restrict__ rowi, const int* __restrict__ coli,
                                                 const float* __restrict__ Wd, const float* __restrict__ bd,
                                                 float* __restrict__ out, int NP, int EL) {
  const int lane = threadIdx.x & 63;
  const int wid = blockIdx.x * 4 + (threadIdx.x >> 6);
  const int nw = gridDim.x * 4;
  const float4 wv = *(const float4*)&Wd[lane * 4];
  const float bdv = bd[0];
  for (int e = wid; e < EL; e += nw) {
    const int r = rowi[e], c = coli[e];
    const u16* hrow = (lane < 32) ? &hf[(size_t)(NP + r) * D128 + lane * 4]
                                  : &hf[(size_t)c * D128 + (lane * 4 - 128)];
    const ushort4 hb = *(const ushort4*)hrow;
    const float x0 = b2f((short)hb.x), x1 = b2f((short)hb.y);
    const float x2 = b2f((short)hb.z), x3 = b2f((short)hb.w);
    float p = x0 * wv.x + x1 * wv.y + x2 * wv.z + x3 * wv.w;
#pragma unroll
    for (int m = 1; m < 64; m <<= 1) p += __shfl_xor(p, m, 64);
    f32x4 st = {x0, x1, x2, x3};
    *(f32x4*)&out[(size_t)EL + (size_t)e * 256 + lane * 4] = st;
    if (lane == 0) out[e] = p + bdv;
  }
}

// ---------------- host ----------------

extern "C" void kernel_launch(void* const* d_in, const int* in_sizes, int n_in,
                              void* d_out, int out_size, void* d_ws, size_t ws_size,
                              hipStream_t stream) {
  const float* x_chem = (const float*)d_in[0];
  const float* x_prot = (const float*)d_in[1];
  const float* Wl = (const float*)d_in[2];
  const float* bl = (const float*)d_in[3];
  const float* Wr = (const float*)d_in[4];
  const float* Wd = (const float*)d_in[5];
  const float* bd = (const float*)d_in[6];
  const int* src = (const int*)d_in[7];
  const int* dst = (const int*)d_in[8];
  const int* row = (const int*)d_in[9];
  const int* col = (const int*)d_in[10];

  int NC = in_sizes[0] / D128;
  int NP = in_sizes[1] / D128;
  int E  = in_sizes[7];
  int EL = in_sizes[9];
  int NT = NP + NC;
  int nchunk = (NT + 2047) / 2048;
  float* out = (float*)d_out;

  char* w = (char*)d_ws;
  size_t szT = (size_t)NT * D128 * 2;
  u16* B0 = (u16*)w; w += szT;
  u16* B1 = (u16*)w; w += szT;
  u16* B2 = (u16*)w; w += szT;
  u16* Wcat = (u16*)w; w += (size_t)6 * 128 * 256 * 2;
  int* deg  = (int*)w; w += (size_t)NT * 4;   // deg,cur contiguous (one memset)
  int* cur  = (int*)w; w += (size_t)NT * 4;
  int* offp = (int*)w; w += (size_t)NT * 4;
  int* adj  = (int*)w; w += (size_t)2 * E * 4;
  if ((size_t)(w - (char*)d_ws) > ws_size) return;

  (void)hipMemsetAsync(deg, 0, (size_t)2 * NT * 4, stream);

  cvt_deg_k<<<2048, 256, 0, stream>>>(x_chem, x_prot, Wl, Wr, src, dst,
                                      B0, Wcat, deg, NP, NT, E);
  scan_k<<<nchunk, 256, 0, stream>>>(deg, offp, NT);
  fill_k<<<(E + 255) / 256, 256, 0, stream>>>(src, dst, offp, cur, adj, NP, E);

  const int tilesP = (NP + 127) >> 7;
  const int tilesC = (NC + 127) >> 7;
  u16* bufs[4] = {B0, B1, B2, B1};   // L0: B0->B1, L1: B1->B2, L2: B2->B1
  for (int l = 0; l < 3; ++l) {
    layer_k<<<tilesP + tilesC, 256, 0, stream>>>(bufs[l], bufs[l + 1], adj, offp, deg,
                                                 Wcat + (size_t)l * 65536,
                                                 bl + (size_t)l * 256,
                                                 NP, NT, tilesP);
  }

  decoder_k<<<2048, 256, 0, stream>>>(B1, row, col, Wd, bd, out, NP, EL);
}

// Round 12
// 483.708 us; speedup vs baseline: 1.8321x; 1.2930x over previous
//
#include <hip/hip_runtime.h>

#define D128 128

typedef __attribute__((ext_vector_type(8))) short bf16x8;
typedef __attribute__((ext_vector_type(4))) float f32x4;
typedef unsigned short u16;
typedef unsigned int u32;

__device__ __forceinline__ u16 f2b(float f) {
  union { float f; u32 u; } x; x.f = f;
  u32 r = x.u + 0x7fffu + ((x.u >> 16) & 1u);
  return (u16)(r >> 16);
}
__device__ __forceinline__ float b2f(short s) {
  union { u32 u; float f; } x; x.u = ((u32)(unsigned short)s) << 16; return x.f;
}

#define GLD16(gp, lp) __builtin_amdgcn_global_load_lds( \
    (const __attribute__((address_space(1))) void*)(gp), \
    (__attribute__((address_space(3))) void*)(lp), 16, 0, 0)

// ---- P0: cvt x -> B0 (combined: protein [0,NP), chem [NP,NT)), W -> Wcat, zero deg+cur ----
__global__ __launch_bounds__(256) void cvt_all_k(const float* __restrict__ xc, const float* __restrict__ xp,
                                                 const float* __restrict__ Wl, const float* __restrict__ Wr,
                                                 u16* __restrict__ B0, u16* __restrict__ Wcat,
                                                 int* __restrict__ zbase, int NP, int NT) {
  const int nqx = NT * 32;
  const int TOT = nqx + 49152 + (2 * NT) / 4;
  for (int i = blockIdx.x * 256 + threadIdx.x; i < TOT; i += gridDim.x * 256) {
    if (i < nqx) {
      const int r = i >> 5, c4 = (i & 31) << 2;
      const float* sp = (r < NP) ? &xp[(size_t)r * D128 + c4]
                                 : &xc[(size_t)(r - NP) * D128 + c4];
      float4 f = *(const float4*)sp;
      uint2 u;
      u.x = (u32)f2b(f.x) | ((u32)f2b(f.y) << 16);
      u.y = (u32)f2b(f.z) | ((u32)f2b(f.w) << 16);
      *(uint2*)&B0[(size_t)i * 4] = u;
    } else if (i < nqx + 49152) {
      const int t = (i - nqx) * 4;
      const int slice = t >> 15, j = (t >> 8) & 127, k = t & 255;
      const float* sw = (k < 128) ? &Wl[(size_t)slice * 16384 + j * 128 + k]
                                  : &Wr[(size_t)slice * 16384 + j * 128 + (k - 128)];
      float4 f = *(const float4*)sw;
      uint2 u;
      u.x = (u32)f2b(f.x) | ((u32)f2b(f.y) << 16);
      u.y = (u32)f2b(f.z) | ((u32)f2b(f.w) << 16);
      *(uint2*)&Wcat[t] = u;
    } else {
      const int z = i - nqx - 49152;
      int4 zv; zv.x = 0; zv.y = 0; zv.z = 0; zv.w = 0;
      ((int4*)zbase)[z] = zv;     // deg and cur contiguous
    }
  }
}

// ---- P1: degrees ----
__global__ __launch_bounds__(256) void degree_k(const int* __restrict__ src, const int* __restrict__ dst,
                                                int* deg, int NP, int E) {
  int e = blockIdx.x * 256 + threadIdx.x;
  if (e >= E) return;
  atomicAdd(&deg[dst[e]], 1);
  atomicAdd(&deg[NP + src[e]], 1);
}

// ---- P2: full exclusive scan in ONE dispatch ----
__global__ __launch_bounds__(256) void scan_k(const int* __restrict__ deg, int* __restrict__ offp, int NT) {
  __shared__ int sh[256];
  const int c = blockIdx.x;
  const int tid = threadIdx.x;
  int pre = 0;
  const int lim = c * 2048;
  for (int i = tid; i < lim; i += 256) pre += deg[i];
  sh[tid] = pre; __syncthreads();
#pragma unroll
  for (int o = 128; o > 0; o >>= 1) {
    if (tid < o) sh[tid] += sh[tid + o];
    __syncthreads();
  }
  const int base_pre = sh[0];
  __syncthreads();
  const int base = lim + tid * 8;
  int v[8]; int s = 0;
#pragma unroll
  for (int u = 0; u < 8; ++u) { int i = base + u; v[u] = (i < NT) ? deg[i] : 0; s += v[u]; }
  sh[tid] = s; __syncthreads();
#pragma unroll
  for (int o = 1; o < 256; o <<= 1) {
    int t = (tid >= o) ? sh[tid - o] : 0;
    __syncthreads();
    sh[tid] += t;
    __syncthreads();
  }
  int run = sh[tid] - s + base_pre;
#pragma unroll
  for (int u = 0; u < 8; ++u) { int i = base + u; if (i < NT) offp[i] = run; run += v[u]; }
}

// ---- P3: fill adjacency (combined ids) ----
__global__ __launch_bounds__(256) void fill_k(const int* __restrict__ src, const int* __restrict__ dst,
                                              const int* __restrict__ offp, int* cur, int* adj,
                                              int NP, int E) {
  int e = blockIdx.x * 256 + threadIdx.x;
  if (e >= E) return;
  const int s = src[e], d = dst[e];
  const int cn = NP + s;
  int pp = atomicAdd(&cur[d], 1);  adj[offp[d] + pp] = cn;
  int pc = atomicAdd(&cur[cn], 1); adj[offp[cn] + pc] = d;
}

// ---- agg: 4 nodes/wave (16-lane groups), 16B/lane bf16x8 gathers, 4-deep ILP ----
__global__ __launch_bounds__(256) void agg_k(const u16* __restrict__ hcur, u16* __restrict__ hnext,
                                             const int* __restrict__ adj, const int* __restrict__ offp,
                                             const int* __restrict__ deg, int NT) {
  const int v = blockIdx.x * 16 + (threadIdx.x >> 4);
  if (v >= NT) return;
  const int l16 = threadIdx.x & 15;
  const int s = offp[v], cnt = deg[v];
  float ac[8] = {0.f, 0.f, 0.f, 0.f, 0.f, 0.f, 0.f, 0.f};
  for (int n = 0; n < cnt; n += 16) {
    int batch = cnt - n; if (batch > 16) batch = 16;
    int idx = (l16 < batch) ? adj[s + n + l16] : 0;
    int j = 0;
    for (; j + 4 <= batch; j += 4) {
      const int i0 = __shfl(idx, j, 16);
      const int i1 = __shfl(idx, j + 1, 16);
      const int i2 = __shfl(idx, j + 2, 16);
      const int i3 = __shfl(idx, j + 3, 16);
      bf16x8 r0 = *(const bf16x8*)&hcur[(size_t)i0 * D128 + l16 * 8];
      bf16x8 r1 = *(const bf16x8*)&hcur[(size_t)i1 * D128 + l16 * 8];
      bf16x8 r2 = *(const bf16x8*)&hcur[(size_t)i2 * D128 + l16 * 8];
      bf16x8 r3 = *(const bf16x8*)&hcur[(size_t)i3 * D128 + l16 * 8];
#pragma unroll
      for (int k = 0; k < 8; ++k)
        ac[k] += (b2f(r0[k]) + b2f(r1[k])) + (b2f(r2[k]) + b2f(r3[k]));
    }
    for (; j < batch; ++j) {
      const int i0 = __shfl(idx, j, 16);
      bf16x8 r0 = *(const bf16x8*)&hcur[(size_t)i0 * D128 + l16 * 8];
#pragma unroll
      for (int k = 0; k < 8; ++k) ac[k] += b2f(r0[k]);
    }
  }
  const float inv = (cnt > 0) ? 1.f / (float)cnt : 0.f;
  uint4 pk;
  pk.x = (u32)f2b(ac[0] * inv) | ((u32)f2b(ac[1] * inv) << 16);
  pk.y = (u32)f2b(ac[2] * inv) | ((u32)f2b(ac[3] * inv) << 16);
  pk.z = (u32)f2b(ac[4] * inv) | ((u32)f2b(ac[5] * inv) << 16);
  pk.w = (u32)f2b(ac[6] * inv) | ((u32)f2b(ac[7] * inv) << 16);
  *(uint4*)&hnext[(size_t)v * D128 + l16 * 8] = pk;
}

// ---- gemm: hnext = relu(concat(hnext, hcur) @ Wcat_l^T + bias), in-place ----
__global__ __launch_bounds__(256) void gemm_both_k(u16* __restrict__ hnext, const u16* __restrict__ hcur,
                                                   const u16* __restrict__ Wcat_l, const float* __restrict__ bl_l,
                                                   int NP, int NT, int tilesP) {
  __shared__ u16 As[128 * 64];
  __shared__ u16 Bs[128 * 64];
  const int t = blockIdx.x;
  const bool isP = t < tilesP;
  const int rbase = isP ? t * 128 : NP + (t - tilesP) * 128;
  const int hi = isP ? NP : NT;
  const u16* __restrict__ W = Wcat_l + (isP ? 0 : 32768);
  const float* __restrict__ bias = bl_l + (isP ? 0 : 128);

  const int tid = threadIdx.x;
  const int w = tid >> 6, lane = tid & 63;
  const int wr = w >> 1, wc = w & 1;
  const int l15 = lane & 15, chi = lane >> 4;

  f32x4 acc[4][4];
#pragma unroll
  for (int m = 0; m < 4; ++m)
#pragma unroll
    for (int n = 0; n < 4; ++n) acc[m][n] = (f32x4){0.f, 0.f, 0.f, 0.f};

  for (int ks = 0; ks < 4; ++ks) {
    const int k0 = ks * 64;
    const u16* Xsrc = (k0 < 128) ? hnext : hcur;
    const int kb = k0 & 127;
    if (ks) __syncthreads();
#pragma unroll
    for (int q = 0; q < 4; ++q) {
      const int ibase = w * 256 + q * 64;
      const int i = ibase + lane;
      const int r = i >> 3;
      const int cg = (i & 7) ^ (r & 7);
      int rr = rbase + r; if (rr >= hi) rr = hi - 1;
      GLD16(Xsrc + (size_t)rr * D128 + kb + cg * 8, (char*)As + ibase * 16);
      GLD16(W + (size_t)r * 256 + k0 + cg * 8, (char*)Bs + ibase * 16);
    }
    __syncthreads();
#pragma unroll
    for (int kk = 0; kk < 2; ++kk) {
      bf16x8 a[4], bfr[4];
      const int c = kk * 4 + chi;
#pragma unroll
      for (int m = 0; m < 4; ++m) {
        const int r = wr * 64 + m * 16 + l15;
        a[m] = *(const bf16x8*)((const char*)As + (r * 8 + (c ^ (r & 7))) * 16);
      }
#pragma unroll
      for (int n = 0; n < 4; ++n) {
        const int j = wc * 64 + n * 16 + l15;
        bfr[n] = *(const bf16x8*)((const char*)Bs + (j * 8 + (c ^ (j & 7))) * 16);
      }
#pragma unroll
      for (int m = 0; m < 4; ++m)
#pragma unroll
        for (int n = 0; n < 4; ++n)
          acc[m][n] = __builtin_amdgcn_mfma_f32_16x16x32_bf16(a[m], bfr[n], acc[m][n], 0, 0, 0);
    }
  }
#pragma unroll
  for (int n = 0; n < 4; ++n) {
    const int col = wc * 64 + n * 16 + l15;
    const float bv = bias[col];
#pragma unroll
    for (int m = 0; m < 4; ++m) {
      const int rb2 = rbase + wr * 64 + m * 16 + chi * 4;
#pragma unroll
      for (int q = 0; q < 4; ++q) {
        const int row = rb2 + q;
        if (row < hi) {
          float vv = acc[m][n][q] + bv;
          vv = vv > 0.f ? vv : 0.f;
          hnext[(size_t)row * D128 + col] = f2b(vv);
        }
      }
    }
  }
}

// ---- decoder: one edge per wave, float4 x-writes ----
__global__ __launch_bounds__(256) void decoder_k(const u16* __restrict__ hf,
                                                 const int* __restrict__ rowi, const int* __restrict__ coli,
                                                 const float* __restrict__ Wd, const float* __restrict__ bd,
                                                 float* __restrict__ out, int NP, int EL) {
  const int lane = threadIdx.x & 63;
  const int wid = blockIdx.x * 4 + (threadIdx.x >> 6);
  const int nw = gridDim.x * 4;
  const float4 wv = *(const float4*)&Wd[lane * 4];
  const float bdv = bd[0];
  for (int e = wid; e < EL; e += nw) {
    const int r = rowi[e], c = coli[e];
    const u16* hrow = (lane < 32) ? &hf[(size_t)(NP + r) * D128 + lane * 4]
                                  : &hf[(size_t)c * D128 + (lane * 4 - 128)];
    const ushort4 hb = *(const ushort4*)hrow;
    const float x0 = b2f((short)hb.x), x1 = b2f((short)hb.y);
    const float x2 = b2f((short)hb.z), x3 = b2f((short)hb.w);
    float p = x0 * wv.x + x1 * wv.y + x2 * wv.z + x3 * wv.w;
#pragma unroll
    for (int m = 1; m < 64; m <<= 1) p += __shfl_xor(p, m, 64);
    f32x4 st = {x0, x1, x2, x3};
    *(f32x4*)&out[(size_t)EL + (size_t)e * 256 + lane * 4] = st;
    if (lane == 0) out[e] = p + bdv;
  }
}

// ---------------- host ----------------

extern "C" void kernel_launch(void* const* d_in, const int* in_sizes, int n_in,
                              void* d_out, int out_size, void* d_ws, size_t ws_size,
                              hipStream_t stream) {
  const float* x_chem = (const float*)d_in[0];
  const float* x_prot = (const float*)d_in[1];
  const float* Wl = (const float*)d_in[2];
  const float* bl = (const float*)d_in[3];
  const float* Wr = (const float*)d_in[4];
  const float* Wd = (const float*)d_in[5];
  const float* bd = (const float*)d_in[6];
  const int* src = (const int*)d_in[7];
  const int* dst = (const int*)d_in[8];
  const int* row = (const int*)d_in[9];
  const int* col = (const int*)d_in[10];

  int NC = in_sizes[0] / D128;
  int NP = in_sizes[1] / D128;
  int E  = in_sizes[7];
  int EL = in_sizes[9];
  int NT = NP + NC;
  int nchunk = (NT + 2047) / 2048;
  float* out = (float*)d_out;

  char* w = (char*)d_ws;
  size_t szT = (size_t)NT * D128 * 2;
  u16* B0 = (u16*)w; w += szT;
  u16* B1 = (u16*)w; w += szT;
  u16* B2 = (u16*)w; w += szT;
  u16* Wcat = (u16*)w; w += (size_t)6 * 128 * 256 * 2;
  int* deg  = (int*)w; w += (size_t)NT * 4;   // deg,cur contiguous (fused zeroing)
  int* cur  = (int*)w; w += (size_t)NT * 4;
  int* offp = (int*)w; w += (size_t)NT * 4;
  int* adj  = (int*)w; w += (size_t)2 * E * 4;
  if ((size_t)(w - (char*)d_ws) > ws_size) return;

  cvt_all_k<<<2048, 256, 0, stream>>>(x_chem, x_prot, Wl, Wr, B0, Wcat, deg, NP, NT);

  int gE = (E + 255) / 256;
  degree_k<<<gE, 256, 0, stream>>>(src, dst, deg, NP, E);
  scan_k<<<nchunk, 256, 0, stream>>>(deg, offp, NT);
  fill_k<<<gE, 256, 0, stream>>>(src, dst, offp, cur, adj, NP, E);

  const int tilesP = (NP + 127) >> 7;
  const int tilesC = (NC + 127) >> 7;
  u16* bufs[4] = {B0, B1, B2, B1};   // L0: B0->B1, L1: B1->B2, L2: B2->B1
  for (int l = 0; l < 3; ++l) {
    const u16* hcur = bufs[l];
    u16* hnext = bufs[l + 1];
    agg_k<<<(NT + 15) / 16, 256, 0, stream>>>(hcur, hnext, adj, offp, deg, NT);
    gemm_both_k<<<tilesP + tilesC, 256, 0, stream>>>(hnext, hcur,
                                                     Wcat + (size_t)l * 65536,
                                                     bl + (size_t)l * 256,
                                                     NP, NT, tilesP);
  }

  decoder_k<<<2048, 256, 0, stream>>>(B1, row, col, Wd, bd, out, NP, EL);
}